// Round 1
// baseline (52900.189 us; speedup 1.0000x reference)
//
#include <hip/hip_runtime.h>
#include <math.h>

// Problem constants (from reference): B=128, T=256, H=E=1024, L=2, EOS=1
#define NB 128
#define NT 256
#define NH 1024
#define NE 1024
#define G4 4096  // 4*H gate rows
#define EOSL 1

// ---------------- workspace layout (float units) ----------------
// z    : [dir(2)][part(2)][G4][NB]            2*2*4096*128 = 2097152
// h_all: [(l*2+dir)][NB][NH]                  4*128*1024   =  524288
// c_all: [(l*2+dir)][NH][NB]                  4*1024*128   =  524288
// Ht   : [dir(2)][NH][NB]                     2*1024*128   =  262144
// fcz  : [kp(8)][NB][NE]                      8*128*1024   = 1048576
// bias : [(l*2+dir)][G4]                      4*4096       =   16384
// feed : 128 int, ended: 128 int
// xbuf : [NB][NE]                             131072   (fallback path)
// P0   : [dir(2)][NE][G4]                     2*1024*4096  = 8388608 (optional)
#define Z_OFF    ((size_t)0)
#define H_OFF    ((size_t)2097152)
#define C_OFF    ((size_t)2621440)
#define HT_OFF   ((size_t)3145728)
#define FCZ_OFF  ((size_t)3407872)
#define BIAS_OFF ((size_t)4456448)
#define FEED_OFF ((size_t)4472832)
#define END_OFF  ((size_t)4472960)
#define XBUF_OFF ((size_t)4473088)
#define P0_OFF   ((size_t)4604160)
#define TOTAL_NOP0_F ((size_t)4604160)
#define TOTAL_P0_F   ((size_t)12992768)

struct GemmDesc {
  const float* in0[2];  // [dir], part-0 input base (k-preoffset), row stride NH
  const float* in1[2];  // [dir], part-1 input base
  const float* W0[2];   // [dir], part-0 weight base (k-preoffset), row stride NH
  const float* W1[2];
  const float* P0[2];   // nullable: acc init for part 0 = P0[feed[b]][n]
  int Kp;               // K extent per part (512 or 1024)
};

// ---------------- init: states, fused biases, feed/ended ----------------
__global__ void k_init(const int* yy, const float* h_t, const float* h_tr,
                       const float* c0, const float* c0r,
                       const float* b_ih, const float* b_hh,
                       const float* b_ihr, const float* b_hhr,
                       float* h_all, float* c_all, float* bias_sum,
                       int* feed, int* ended)
{
  int idx = blockIdx.x * 256 + threadIdx.x;  // up to 524288
  if (idx < 4 * NB * NH) {  // h_all[(l*2+dir)][b][n]
    int ld = idx / (NB * NH); int l = ld >> 1, dir = ld & 1;
    int rem = idx % (NB * NH);
    h_all[idx] = (dir ? h_tr : h_t)[(size_t)l * NB * NH + rem];
  }
  if (idx < 4 * NH * NB) {  // c_all[(l*2+dir)][n][b]
    int ld = idx / (NH * NB); int l = ld >> 1, dir = ld & 1;
    int rem = idx % (NH * NB); int n = rem / NB;
    c_all[idx] = (dir ? c0r : c0)[l * NH + n];
  }
  if (idx < 4 * G4) {  // bias_sum[(l*2+dir)][m]
    int ld = idx / G4; int l = ld >> 1, dir = ld & 1;
    int m = idx % G4;
    bias_sum[idx] = (dir ? b_ihr : b_ih)[l * G4 + m] + (dir ? b_hhr : b_hh)[l * G4 + m];
  }
  if (idx < NB) { feed[idx] = yy[idx * NT]; ended[idx] = 0; }
}

// ---------------- P0 = emb @ W_ih0.T  per dir:  [NE][G4] ----------------
__global__ __launch_bounds__(256) void k_p0(const float* emb, const float* W_ih,
                                            const float* W_ihr, float* P0)
{
  int dir = blockIdx.z;
  const float* W = dir ? W_ihr : W_ih;           // layer 0 slice
  float* P = P0 + (size_t)dir * NE * G4;
  int e0 = blockIdx.x * 64, n0 = blockIdx.y * 64;
  __shared__ __align__(16) float a_s[64][36];
  __shared__ __align__(16) float w_s[64][36];
  int t = threadIdx.x;
  int eg = t >> 4;   // 16 groups * 4 e
  int ng = t & 15;   // 4 n strided by 16
  float acc[4][4] = {};
  for (int kc = 0; kc < 1024; kc += 32) {
    #pragma unroll
    for (int i = 0; i < 2; i++) {
      int flat = t + 256 * i, r = flat >> 3, f4i = flat & 7;
      *(float4*)&a_s[r][f4i * 4] = *(const float4*)(emb + (size_t)(e0 + r) * NE + kc + f4i * 4);
      *(float4*)&w_s[r][f4i * 4] = *(const float4*)(W   + (size_t)(n0 + r) * NH + kc + f4i * 4);
    }
    __syncthreads();
    #pragma unroll
    for (int kq = 0; kq < 8; kq++) {
      float4 a4[4], w4[4];
      #pragma unroll
      for (int ie = 0; ie < 4; ie++) a4[ie] = *(const float4*)&a_s[eg * 4 + ie][kq * 4];
      #pragma unroll
      for (int jn = 0; jn < 4; jn++) w4[jn] = *(const float4*)&w_s[ng + 16 * jn][kq * 4];
      #pragma unroll
      for (int ie = 0; ie < 4; ie++)
        #pragma unroll
        for (int jn = 0; jn < 4; jn++)
          acc[ie][jn] += a4[ie].x * w4[jn].x + a4[ie].y * w4[jn].y +
                         a4[ie].z * w4[jn].z + a4[ie].w * w4[jn].w;
    }
    __syncthreads();
  }
  for (int ie = 0; ie < 4; ie++)
    for (int jn = 0; jn < 4; jn++)
      P[(size_t)(e0 + eg * 4 + ie) * G4 + n0 + ng + 16 * jn] = acc[ie][jn];
}

// ---------------- fallback: xbuf[b][k] = emb[feed[b]][k] ----------------
__global__ void k_gather(const float* emb, const int* feed, float* xbuf)
{
  int idx = blockIdx.x * 256 + threadIdx.x;  // 32768 float4
  int b = idx >> 8, k4 = idx & 255;
  ((float4*)xbuf)[idx] = ((const float4*)(emb + (size_t)feed[b] * NE))[k4];
}

// ---------------- main cell GEMM: z[(dir*2+part)][n][b] ----------------
// tile: 128b x 64n, 256 thr, thread = 4b x 8n acc. n strided (n_sub + 8*jn)
// so consecutive-lane W_s reads hit distinct bank quads; in_s k-quads are
// XOR-swizzled by b-group to kill the stride-144 4-way conflict.
__global__ __launch_bounds__(256) void k_gemm(GemmDesc d, const int* feed, float* z)
{
  int nt = blockIdx.x, q = blockIdx.y;
  int dir = q >> 1, part = q & 1;
  const float* in = part ? d.in1[dir] : d.in0[dir];
  const float* W  = part ? d.W1[dir]  : d.W0[dir];
  int n0 = nt * 64;
  __shared__ __align__(16) float in_s[128][36];
  __shared__ __align__(16) float w_s[64][36];
  int t = threadIdx.x;
  int n_sub = t & 7;
  int bg = t >> 3;
  int b0 = bg * 4;
  float acc[8][4];
  const float* P = d.P0[dir];
  if (P != nullptr && part == 0) {
    #pragma unroll
    for (int ib = 0; ib < 4; ib++) {
      int fb = feed[b0 + ib];
      const float* Prow = P + (size_t)fb * G4 + n0;
      #pragma unroll
      for (int jn = 0; jn < 8; jn++) acc[jn][ib] = Prow[n_sub + 8 * jn];
    }
  } else {
    #pragma unroll
    for (int jn = 0; jn < 8; jn++)
      #pragma unroll
      for (int ib = 0; ib < 4; ib++) acc[jn][ib] = 0.f;
  }
  for (int kc = 0; kc < d.Kp; kc += 32) {
    #pragma unroll
    for (int i = 0; i < 4; i++) {  // stage in: 128 x 32
      int flat = t + 256 * i, r = flat >> 3, f4i = flat & 7;
      float4 v = *(const float4*)(in + (size_t)r * NH + kc + f4i * 4);
      int sw = (f4i ^ (r >> 2)) & 7;
      *(float4*)&in_s[r][sw * 4] = v;
    }
    #pragma unroll
    for (int i = 0; i < 2; i++) {  // stage W: 64 x 32
      int flat = t + 256 * i, r = flat >> 3, f4i = flat & 7;
      *(float4*)&w_s[r][f4i * 4] = *(const float4*)(W + (size_t)(n0 + r) * NH + kc + f4i * 4);
    }
    __syncthreads();
    #pragma unroll
    for (int kq = 0; kq < 8; kq++) {
      int ksw = (kq ^ bg) & 7;
      float4 a4[4];
      #pragma unroll
      for (int ib = 0; ib < 4; ib++) a4[ib] = *(const float4*)&in_s[b0 + ib][ksw * 4];
      float4 w4[8];
      #pragma unroll
      for (int jn = 0; jn < 8; jn++) w4[jn] = *(const float4*)&w_s[n_sub + 8 * jn][kq * 4];
      #pragma unroll
      for (int jn = 0; jn < 8; jn++)
        #pragma unroll
        for (int ib = 0; ib < 4; ib++)
          acc[jn][ib] += a4[ib].x * w4[jn].x + a4[ib].y * w4[jn].y +
                         a4[ib].z * w4[jn].z + a4[ib].w * w4[jn].w;
    }
    __syncthreads();
  }
  float* zb = z + ((size_t)(dir * 2 + part) * G4 + n0) * NB;
  #pragma unroll
  for (int jn = 0; jn < 8; jn++) {
    int n = n_sub + 8 * jn;
    float4 v = make_float4(acc[jn][0], acc[jn][1], acc[jn][2], acc[jn][3]);
    *(float4*)(zb + (size_t)n * NB + b0) = v;
  }
}

__device__ __forceinline__ float sigmoid_stable(float x) {
  if (x >= 0.f) return 1.f / (1.f + expf(-x));
  float ex = expf(x);
  return ex / (1.f + ex);
}

// ---------------- gates: z parts + bias -> h, c (and Ht for layer 1) ----------------
__global__ void k_gates(const float* z, const float* bias /*layer base [2][G4]*/,
                        float* h /*layer base [2][NB][NH]*/,
                        float* c /*layer base [2][NH][NB]*/,
                        float* Ht /*[2][NH][NB] or null*/)
{
  int dir = blockIdx.y;
  int t = threadIdx.x;
  int n = blockIdx.x * 2 + (t >> 7);
  int b = t & 127;
  const float* z0 = z + (size_t)(dir * 2 + 0) * G4 * NB;
  const float* z1 = z + (size_t)(dir * 2 + 1) * G4 * NB;
  const float* bs = bias + (size_t)dir * G4;
  float zi = z0[(size_t)(0 * NH + n) * NB + b] + z1[(size_t)(0 * NH + n) * NB + b] + bs[0 * NH + n];
  float zf = z0[(size_t)(1 * NH + n) * NB + b] + z1[(size_t)(1 * NH + n) * NB + b] + bs[1 * NH + n];
  float zg = z0[(size_t)(2 * NH + n) * NB + b] + z1[(size_t)(2 * NH + n) * NB + b] + bs[2 * NH + n];
  float zo = z0[(size_t)(3 * NH + n) * NB + b] + z1[(size_t)(3 * NH + n) * NB + b] + bs[3 * NH + n];
  float si = sigmoid_stable(zi);
  float sf = sigmoid_stable(zf);
  float tg = tanhf(zg);
  float so = sigmoid_stable(zo);
  float* cp = c + ((size_t)dir * NH + n) * NB + b;
  float cn = sf * (*cp) + si * tg;
  *cp = cn;
  float hn = so * tanhf(cn);
  h[((size_t)dir * NB + b) * NH + n] = hn;
  if (Ht) Ht[((size_t)dir * NH + n) * NB + b] = hn;
}

// ---------------- FC GEMM: fcz[kp][b][e] partials of wh @ fc_W.T ----------------
// wh row b is the contiguous slice Ht_dir.flat[ (b&63)*2048 : +2048 ].
__global__ __launch_bounds__(256) void k_fc(const float* Ht, const float* fc_W, float* fcz)
{
  int et = blockIdx.x, kp = blockIdx.y;
  int e0 = et * 64;
  int k00 = kp * 256;
  __shared__ __align__(16) float in_s[128][36];
  __shared__ __align__(16) float w_s[64][36];
  int t = threadIdx.x, e_sub = t & 7, bg = t >> 3, b0 = bg * 4;
  float acc[8][4] = {};
  for (int kc = 0; kc < 256; kc += 32) {
    #pragma unroll
    for (int i = 0; i < 4; i++) {
      int flat = t + 256 * i, r = flat >> 3, f4i = flat & 7;
      const float* row = Ht + (r >= 64 ? (size_t)NH * NB + (size_t)(r - 64) * 2048
                                       : (size_t)r * 2048);
      float4 v = *(const float4*)(row + k00 + kc + f4i * 4);
      int sw = (f4i ^ (r >> 2)) & 7;
      *(float4*)&in_s[r][sw * 4] = v;
    }
    #pragma unroll
    for (int i = 0; i < 2; i++) {
      int flat = t + 256 * i, r = flat >> 3, f4i = flat & 7;
      *(float4*)&w_s[r][f4i * 4] =
          *(const float4*)(fc_W + (size_t)(e0 + r) * 2048 + k00 + kc + f4i * 4);
    }
    __syncthreads();
    #pragma unroll
    for (int kq = 0; kq < 8; kq++) {
      int ksw = (kq ^ bg) & 7;
      float4 a4[4];
      #pragma unroll
      for (int ib = 0; ib < 4; ib++) a4[ib] = *(const float4*)&in_s[b0 + ib][ksw * 4];
      float4 w4[8];
      #pragma unroll
      for (int je = 0; je < 8; je++) w4[je] = *(const float4*)&w_s[e_sub + 8 * je][kq * 4];
      #pragma unroll
      for (int je = 0; je < 8; je++)
        #pragma unroll
        for (int ib = 0; ib < 4; ib++)
          acc[je][ib] += a4[ib].x * w4[je].x + a4[ib].y * w4[je].y +
                         a4[ib].z * w4[je].z + a4[ib].w * w4[je].w;
    }
    __syncthreads();
  }
  for (int je = 0; je < 8; je++) {
    int e = e0 + e_sub + 8 * je;
    for (int ib = 0; ib < 4; ib++)
      fcz[((size_t)kp * NB + b0 + ib) * NE + e] = acc[je][ib];
  }
}

// ---------------- finalize: logits, override, argmax, state, softmax ----------------
__global__ void k_final(const float* fcz, const float* fc_b, int* feed, int* ended,
                        float* out, int tstep)
{
  int b = blockIdx.x;
  int t = threadIdx.x;
  __shared__ float sval[256];
  __shared__ int   sidx[256];
  __shared__ float ssum[256];
  bool end = (ended[b] != 0);
  float v[4];
  int e_base = t * 4;
  #pragma unroll
  for (int j = 0; j < 4; j++) {
    int e = e_base + j;
    float s = fc_b[e];
    #pragma unroll
    for (int p = 0; p < 8; p++) s += fcz[((size_t)p * NB + b) * NE + e];
    v[j] = end ? (e == EOSL ? 1.f : 0.f) : s;
  }
  // local argmax, ascending e, strict > keeps first occurrence
  float bv = v[0]; int bi = e_base;
  #pragma unroll
  for (int j = 1; j < 4; j++) if (v[j] > bv) { bv = v[j]; bi = e_base + j; }
  sval[t] = bv; sidx[t] = bi;
  __syncthreads();
  for (int s = 128; s > 0; s >>= 1) {
    if (t < s) {
      float ov = sval[t + s]; int oi = sidx[t + s];
      if (ov > sval[t] || (ov == sval[t] && oi < sidx[t])) { sval[t] = ov; sidx[t] = oi; }
    }
    __syncthreads();
  }
  float m = sval[0]; int label = sidx[0];
  float ls = 0.f;
  #pragma unroll
  for (int j = 0; j < 4; j++) { v[j] = expf(v[j] - m); ls += v[j]; }
  ssum[t] = ls;
  __syncthreads();
  for (int s = 128; s > 0; s >>= 1) { if (t < s) ssum[t] += ssum[t + s]; __syncthreads(); }
  float inv = 1.f / ssum[0];
  float* orow = out + ((size_t)b * NT + tstep) * NE + e_base;
  #pragma unroll
  for (int j = 0; j < 4; j++) orow[j] = v[j] * inv;
  if (t == 0) {
    feed[b] = label;                       // ended rows: onehot argmax == EOS
    ended[b] = (end || label == EOSL) ? 1 : 0;
  }
}

extern "C" void kernel_launch(void* const* d_in, const int* in_sizes, int n_in,
                              void* d_out, int out_size, void* d_ws, size_t ws_size,
                              hipStream_t stream)
{
  const int*   yy    = (const int*)d_in[0];
  const float* h_t   = (const float*)d_in[1];
  const float* h_tr  = (const float*)d_in[2];
  // d_in[3] x_lens: unused by the reference
  const float* emb   = (const float*)d_in[4];
  const float* W_ih  = (const float*)d_in[5];
  const float* W_hh  = (const float*)d_in[6];
  const float* b_ih  = (const float*)d_in[7];
  const float* b_hh  = (const float*)d_in[8];
  const float* W_ihr = (const float*)d_in[9];
  const float* W_hhr = (const float*)d_in[10];
  const float* b_ihr = (const float*)d_in[11];
  const float* b_hhr = (const float*)d_in[12];
  const float* c0    = (const float*)d_in[13];
  const float* c0r   = (const float*)d_in[14];
  const float* fc_W  = (const float*)d_in[15];
  const float* fc_b  = (const float*)d_in[16];
  float* out = (float*)d_out;

  float* ws = (float*)d_ws;
  float* z    = ws + Z_OFF;
  float* h_all = ws + H_OFF;
  float* c_all = ws + C_OFF;
  float* Ht   = ws + HT_OFF;
  float* fcz  = ws + FCZ_OFF;
  float* bias = ws + BIAS_OFF;
  int* feed  = (int*)(ws + FEED_OFF);
  int* ended = (int*)(ws + END_OFF);
  float* xbuf = ws + XBUF_OFF;
  float* P0   = ws + P0_OFF;
  bool useP0 = ws_size >= TOTAL_P0_F * sizeof(float);

  k_init<<<2048, 256, 0, stream>>>(yy, h_t, h_tr, c0, c0r, b_ih, b_hh, b_ihr, b_hhr,
                                   h_all, c_all, bias, feed, ended);
  if (useP0)
    k_p0<<<dim3(16, 64, 2), 256, 0, stream>>>(emb, W_ih, W_ihr, P0);

  const float* Whh0[2] = { W_hh,  W_hhr };               // layer 0
  const float* Wih0[2] = { W_ih,  W_ihr };
  const float* Wih1[2] = { W_ih + (size_t)G4 * NH,  W_ihr + (size_t)G4 * NH };
  const float* Whh1[2] = { W_hh + (size_t)G4 * NH,  W_hhr + (size_t)G4 * NH };
  float* h0[2] = { h_all + (size_t)0 * NB * NH, h_all + (size_t)1 * NB * NH };
  float* h1[2] = { h_all + (size_t)2 * NB * NH, h_all + (size_t)3 * NB * NH };

  GemmDesc d0, d1;
  if (useP0) {
    for (int dir = 0; dir < 2; dir++) {
      d0.in0[dir] = h0[dir];        d0.W0[dir] = Whh0[dir];
      d0.in1[dir] = h0[dir] + 512;  d0.W1[dir] = Whh0[dir] + 512;
      d0.P0[dir]  = P0 + (size_t)dir * NE * G4;
    }
    d0.Kp = 512;
  } else {
    for (int dir = 0; dir < 2; dir++) {
      d0.in0[dir] = xbuf;           d0.W0[dir] = Wih0[dir];
      d0.in1[dir] = h0[dir];        d0.W1[dir] = Whh0[dir];
      d0.P0[dir]  = nullptr;
    }
    d0.Kp = 1024;
  }
  for (int dir = 0; dir < 2; dir++) {
    d1.in0[dir] = h0[dir];  d1.W0[dir] = Wih1[dir];
    d1.in1[dir] = h1[dir];  d1.W1[dir] = Whh1[dir];
    d1.P0[dir]  = nullptr;
  }
  d1.Kp = 1024;

  for (int t = 0; t < NT; t++) {
    if (!useP0)
      k_gather<<<128, 256, 0, stream>>>(emb, feed, xbuf);
    k_gemm<<<dim3(64, 4), 256, 0, stream>>>(d0, feed, z);
    k_gates<<<dim3(512, 2), 256, 0, stream>>>(z, bias + 0 * G4,
                                              h_all + (size_t)0 * NB * NH,
                                              c_all + (size_t)0 * NH * NB, nullptr);
    k_gemm<<<dim3(64, 4), 256, 0, stream>>>(d1, feed, z);
    k_gates<<<dim3(512, 2), 256, 0, stream>>>(z, bias + 2 * G4,
                                              h_all + (size_t)2 * NB * NH,
                                              c_all + (size_t)2 * NH * NB, Ht);
    k_fc<<<dim3(16, 8), 256, 0, stream>>>(Ht, fc_W, fcz);
    k_final<<<128, 256, 0, stream>>>(fcz, fc_b, feed, ended, out, t);
  }
}

// Round 2
// 38516.498 us; speedup vs baseline: 1.3734x; 1.3734x over previous
//
#include <hip/hip_runtime.h>
#include <math.h>

// B=128, T=256, H=E=1024, L=2, EOS=1
#define NB 128
#define NT 256
#define NH 1024
#define NE 1024
#define G4 4096
#define EOSL 1

// ---------------- workspace layout (float units) ----------------
#define ZP_OFF   ((size_t)0)          // zp  [4ks][2dir][4096][128] = 4,194,304
#define Z0T_OFF  ((size_t)4194304)    // z0T [2dir][4096][128]      = 1,048,576
#define HIN_OFF  ((size_t)5242880)    // hin [2dir][2048][128]      =   524,288
#define C_OFF    ((size_t)5767168)    // c   [(l*2+dir)][1024][128] =   524,288
#define HT_OFF   ((size_t)6291456)    // Ht  [2dir][1024][128]      =   262,144
#define FCZ_OFF  ((size_t)6553600)    // fcz [8][128][1024]         = 1,048,576
#define BIAS_OFF ((size_t)7602176)    // bias[(l*2+dir)][4096]      =    16,384
#define FEED_OFF ((size_t)7618560)    // 128 int
#define END_OFF  ((size_t)7618688)    // 128 int
#define XH_OFF   ((size_t)7618816)    // xh  [2dir][2048][128]      = 1,048,576 (fallback)
#define P0_OFF   ((size_t)8667392)    // P0  [2dir][1024][4096]     = 8,388,608
#define TOTAL_FB_F ((size_t)8667392)
#define TOTAL_P0_F ((size_t)17056000)

struct GD {
  const float* in[2];   // [dir] base, rows [k][128b]
  const float* W[8];    // [dir*4+ks], row stride 1024, col-preoffset to ks chunk
  int KB;               // K per block (256 or 512)
};

__device__ __forceinline__ void fma4(float4& d, float s, const float4 a) {
  d.x = fmaf(s, a.x, d.x); d.y = fmaf(s, a.y, d.y);
  d.z = fmaf(s, a.z, d.z); d.w = fmaf(s, a.w, d.w);
}
__device__ __forceinline__ void add4(float4& d, const float4 a) {
  d.x += a.x; d.y += a.y; d.z += a.z; d.w += a.w;
}
__device__ __forceinline__ float sigmoid_stable(float x) {
  if (x >= 0.f) return 1.f / (1.f + expf(-x));
  float ex = expf(x);
  return ex / (1.f + ex);
}

// ---------------- init: hin transpose, c, fused bias, feed/ended ----------------
__global__ void k_init(const int* yy, const float* h_t, const float* h_tr,
                       const float* c0, const float* c0r,
                       const float* b_ih, const float* b_hh,
                       const float* b_ihr, const float* b_hhr,
                       float* hin, float* xh, int do_xh,
                       float* call, float* bias, int* feed, int* ended)
{
  int idx = blockIdx.x * 256 + threadIdx.x;   // 2048 blocks -> 524288
  if (idx < 2 * 2048 * 128) {                 // hin[dir][l*1024+n][b]
    int dir = idx / (2048 * 128); int rem = idx % (2048 * 128);
    int row = rem >> 7, b = rem & 127;
    int l = row >> 10, n = row & 1023;
    const float* src = dir ? h_tr : h_t;
    float v = src[((size_t)l * 128 + b) * 1024 + n];
    hin[idx] = v;
    if (do_xh && l == 0)
      xh[(size_t)dir * 2048 * 128 + (size_t)(1024 + n) * 128 + b] = v;
  }
  if (idx < 4 * 1024 * 128) {                 // c[(l*2+dir)][n][b]
    int ld = idx / (1024 * 128); int l = ld >> 1, dir = ld & 1;
    int rem = idx % (1024 * 128); int n = rem >> 7;
    call[idx] = (dir ? c0r : c0)[l * 1024 + n];
  }
  if (idx < 4 * 4096) {                       // bias[(l*2+dir)][m]
    int ld = idx / 4096; int l = ld >> 1, dir = ld & 1;
    int m = idx & 4095;
    bias[idx] = (dir ? b_ihr : b_ih)[l * 4096 + m] + (dir ? b_hhr : b_hh)[l * 4096 + m];
  }
  if (idx < NB) { feed[idx] = yy[idx * NT]; ended[idx] = 0; }
}

// ---------------- P0 = emb @ W_ih0.T per dir: [dir][e 1024][n 4096] ----------------
__global__ __launch_bounds__(256) void k_p0(const float* emb, const float* W_ih,
                                            const float* W_ihr, float* P0)
{
  int dir = blockIdx.z;
  const float* W = dir ? W_ihr : W_ih;
  float* P = P0 + (size_t)dir * NE * G4;
  int e0 = blockIdx.x * 64, n0 = blockIdx.y * 64;
  __shared__ __align__(16) float a_s[64][36];
  __shared__ __align__(16) float w_s[64][36];
  int t = threadIdx.x;
  int eg = t >> 4, ng = t & 15;
  float acc[4][4] = {};
  for (int kc = 0; kc < 1024; kc += 32) {
    #pragma unroll
    for (int i = 0; i < 2; i++) {
      int flat = t + 256 * i, r = flat >> 3, f4i = flat & 7;
      *(float4*)&a_s[r][f4i * 4] = *(const float4*)(emb + (size_t)(e0 + r) * NE + kc + f4i * 4);
      *(float4*)&w_s[r][f4i * 4] = *(const float4*)(W   + (size_t)(n0 + r) * NH + kc + f4i * 4);
    }
    __syncthreads();
    #pragma unroll
    for (int kq = 0; kq < 8; kq++) {
      float4 a4[4], w4[4];
      #pragma unroll
      for (int ie = 0; ie < 4; ie++) a4[ie] = *(const float4*)&a_s[eg * 4 + ie][kq * 4];
      #pragma unroll
      for (int jn = 0; jn < 4; jn++) w4[jn] = *(const float4*)&w_s[ng + 16 * jn][kq * 4];
      #pragma unroll
      for (int ie = 0; ie < 4; ie++)
        #pragma unroll
        for (int jn = 0; jn < 4; jn++)
          acc[ie][jn] += a4[ie].x * w4[jn].x + a4[ie].y * w4[jn].y +
                         a4[ie].z * w4[jn].z + a4[ie].w * w4[jn].w;
    }
    __syncthreads();
  }
  for (int ie = 0; ie < 4; ie++)
    for (int jn = 0; jn < 4; jn++)
      P[(size_t)(e0 + eg * 4 + ie) * G4 + n0 + ng + 16 * jn] = acc[ie][jn];
}

// ------------ gather-transpose: dst[dir][n][b] = src[dir][feed[b]][n] ------------
// grid (srcCols/256, 4 btiles, 2 dirs), 256 thr
__global__ void k_gatherT(const float* src, long srcDirStride, int srcCols,
                          const int* feed, float* dst, long dstDirStride, int dstRowOff)
{
  __shared__ float tile[32 * 257];
  int t = threadIdx.x;
  int n0 = blockIdx.x * 256, b0 = blockIdx.y * 32, dir = blockIdx.z;
  const float* s = src + (size_t)dir * srcDirStride;
  #pragma unroll
  for (int i = 0; i < 8; i++) {
    int idx = t + 256 * i; int br = idx >> 6, cf = idx & 63;
    int row = feed[b0 + br];
    float4 v = *(const float4*)(s + (size_t)row * srcCols + n0 + cf * 4);
    tile[br * 257 + cf * 4 + 0] = v.x;
    tile[br * 257 + cf * 4 + 1] = v.y;
    tile[br * 257 + cf * 4 + 2] = v.z;
    tile[br * 257 + cf * 4 + 3] = v.w;
  }
  __syncthreads();
  #pragma unroll
  for (int i = 0; i < 8; i++) {
    int idx = t + 256 * i; int nr = idx >> 3, cf = idx & 7;
    float4 v;
    v.x = tile[(cf * 4 + 0) * 257 + nr];
    v.y = tile[(cf * 4 + 1) * 257 + nr];
    v.z = tile[(cf * 4 + 2) * 257 + nr];
    v.w = tile[(cf * 4 + 3) * 257 + nr];
    *(float4*)(dst + (size_t)dir * dstDirStride + (size_t)(dstRowOff + n0 + nr) * 128 + b0 + cf * 4) = v;
  }
}

// ---------------- main cell GEMM: zp[ks][dir][4096 n][128 b] partials ----------------
// 512 thr = 2 halves x 256; block tile 128b x 128n; thread 8b x 8n; in-block K-split-2
__global__ __launch_bounds__(512) void k_gemm(GD d, float* zp)
{
  int nt = blockIdx.x, ks = blockIdx.y, dir = blockIdx.z;
  int tid = threadIdx.x; int H = tid >> 8; int t = tid & 255;
  __shared__ __align__(16) float smem[17408];
  float* in_s = smem + H * 4096;           // [32 k][128 b]
  float* w_s  = smem + 8192 + H * 4608;    // [128 n][36]
  int n0 = nt * 128;
  int KBh = d.KB >> 1;
  const float* inb = d.in[dir] + (size_t)(ks * d.KB + H * KBh) * 128;
  const float* Wb  = d.W[dir * 4 + ks] + H * KBh;
  int n_sub = t & 7, bg = (t >> 3) & 15, nhi = t >> 7;
  int b0 = bg * 8;
  float4 acc0[8], acc1[8];
  #pragma unroll
  for (int j = 0; j < 8; j++) { acc0[j] = make_float4(0,0,0,0); acc1[j] = make_float4(0,0,0,0); }

  for (int kc = 0; kc < KBh; kc += 32) {
    #pragma unroll
    for (int i = 0; i < 4; i++) {        // stage in: 32k x 128b (contiguous rows)
      int idx = t + 256 * i; int k = idx >> 5, b4 = idx & 31;
      *(float4*)&in_s[k * 128 + b4 * 4] = *(const float4*)(inb + (size_t)(kc + k) * 128 + b4 * 4);
    }
    #pragma unroll
    for (int i = 0; i < 4; i++) {        // stage W: 128n x 32k, pad-36 rows
      int idx = t + 256 * i; int r = idx >> 3, f = idx & 7;
      *(float4*)&w_s[r * 36 + f * 4] = *(const float4*)(Wb + (size_t)(n0 + r) * 1024 + kc + f * 4);
    }
    __syncthreads();
    #pragma unroll
    for (int kq = 0; kq < 8; kq++) {
      float4 a0[4], a1[4];
      #pragma unroll
      for (int k = 0; k < 4; k++) {
        const float* ip = in_s + (kq * 4 + k) * 128 + b0;
        a0[k] = *(const float4*)ip;
        a1[k] = *(const float4*)(ip + 4);
      }
      #pragma unroll
      for (int j = 0; j < 8; j++) {
        const float4 w = *(const float4*)&w_s[(nhi * 64 + n_sub + 8 * j) * 36 + kq * 4];
        fma4(acc0[j], w.x, a0[0]); fma4(acc1[j], w.x, a1[0]);
        fma4(acc0[j], w.y, a0[1]); fma4(acc1[j], w.y, a1[1]);
        fma4(acc0[j], w.z, a0[2]); fma4(acc1[j], w.z, a1[2]);
        fma4(acc0[j], w.w, a0[3]); fma4(acc1[j], w.w, a1[3]);
      }
    }
    __syncthreads();
  }
  // in-block reduction: half1 -> LDS -> half0 adds, stores
  float* red = smem;                      // [256][68]
  if (H == 1) {
    #pragma unroll
    for (int j = 0; j < 8; j++) {
      *(float4*)&red[t * 68 + j * 8]     = acc0[j];
      *(float4*)&red[t * 68 + j * 8 + 4] = acc1[j];
    }
  }
  __syncthreads();
  if (H == 0) {
    #pragma unroll
    for (int j = 0; j < 8; j++) {
      add4(acc0[j], *(const float4*)&red[t * 68 + j * 8]);
      add4(acc1[j], *(const float4*)&red[t * 68 + j * 8 + 4]);
      int n = n0 + nhi * 64 + n_sub + 8 * j;
      float* zb = zp + ((size_t)(ks * 2 + dir) * 4096 + n) * 128 + b0;
      *(float4*)zb = acc0[j];
      *(float4*)(zb + 4) = acc1[j];
    }
  }
}

// ---------------- gates: sum 4 zp partials (+z0T) + bias -> h, c ----------------
// grid (128, 2 dirs), 256 thr; thread = (h-unit n, 4 b)
__global__ void k_gates(const float* zp, const float* z0T, const float* bias,
                        float* c, float* hin, int hrowoff,
                        float* hB, long hBdirstride, int hBrowoff)
{
  int t = threadIdx.x;
  int idx = blockIdx.x * 256 + t;
  int n = idx >> 5, cc = (idx & 31) << 2;
  int dir = blockIdx.y;
  float4 g[4];
  #pragma unroll
  for (int gg = 0; gg < 4; gg++) {
    int row = gg * 1024 + n;
    float4 s = *(const float4*)(zp + ((size_t)dir * 4096 + row) * 128 + cc);
    #pragma unroll
    for (int ksx = 1; ksx < 4; ksx++)
      add4(s, *(const float4*)(zp + ((size_t)(ksx * 2 + dir) * 4096 + row) * 128 + cc));
    if (z0T)
      add4(s, *(const float4*)(z0T + ((size_t)dir * 4096 + row) * 128 + cc));
    float b = bias[dir * 4096 + row];
    s.x += b; s.y += b; s.z += b; s.w += b;
    g[gg] = s;
  }
  float* cp = c + ((size_t)dir * 1024 + n) * 128 + cc;
  float4 cold = *(float4*)cp;
  float4 cn, hn;
  cn.x = sigmoid_stable(g[1].x) * cold.x + sigmoid_stable(g[0].x) * tanhf(g[2].x);
  cn.y = sigmoid_stable(g[1].y) * cold.y + sigmoid_stable(g[0].y) * tanhf(g[2].y);
  cn.z = sigmoid_stable(g[1].z) * cold.z + sigmoid_stable(g[0].z) * tanhf(g[2].z);
  cn.w = sigmoid_stable(g[1].w) * cold.w + sigmoid_stable(g[0].w) * tanhf(g[2].w);
  hn.x = sigmoid_stable(g[3].x) * tanhf(cn.x);
  hn.y = sigmoid_stable(g[3].y) * tanhf(cn.y);
  hn.z = sigmoid_stable(g[3].z) * tanhf(cn.z);
  hn.w = sigmoid_stable(g[3].w) * tanhf(cn.w);
  *(float4*)cp = cn;
  *(float4*)(hin + (size_t)dir * (2048 * 128) + (size_t)(hrowoff + n) * 128 + cc) = hn;
  if (hB)
    *(float4*)(hB + (size_t)dir * hBdirstride + (size_t)(hBrowoff + n) * 128 + cc) = hn;
}

// ---------------- FC GEMM: fcz[kp][b][e] partials of wh @ fc_W.T ----------------
__global__ __launch_bounds__(256) void k_fc(const float* Ht, const float* fc_W, float* fcz)
{
  int et = blockIdx.x, kp = blockIdx.y;
  int e0 = et * 64;
  int k00 = kp * 256;
  __shared__ __align__(16) float in_s[128][36];
  __shared__ __align__(16) float w_s[64][36];
  int t = threadIdx.x, e_sub = t & 7, bg = t >> 3, b0 = bg * 4;
  float acc[8][4] = {};
  for (int kc = 0; kc < 256; kc += 32) {
    #pragma unroll
    for (int i = 0; i < 4; i++) {
      int flat = t + 256 * i, r = flat >> 3, f4i = flat & 7;
      const float* row = Ht + (r >= 64 ? (size_t)NH * NB + (size_t)(r - 64) * 2048
                                       : (size_t)r * 2048);
      float4 v = *(const float4*)(row + k00 + kc + f4i * 4);
      int sw = (f4i ^ (r >> 2)) & 7;
      *(float4*)&in_s[r][sw * 4] = v;
    }
    #pragma unroll
    for (int i = 0; i < 2; i++) {
      int flat = t + 256 * i, r = flat >> 3, f4i = flat & 7;
      *(float4*)&w_s[r][f4i * 4] =
          *(const float4*)(fc_W + (size_t)(e0 + r) * 2048 + k00 + kc + f4i * 4);
    }
    __syncthreads();
    #pragma unroll
    for (int kq = 0; kq < 8; kq++) {
      int ksw = (kq ^ bg) & 7;
      float4 a4[4];
      #pragma unroll
      for (int ib = 0; ib < 4; ib++) a4[ib] = *(const float4*)&in_s[b0 + ib][ksw * 4];
      float4 w4[8];
      #pragma unroll
      for (int je = 0; je < 8; je++) w4[je] = *(const float4*)&w_s[e_sub + 8 * je][kq * 4];
      #pragma unroll
      for (int je = 0; je < 8; je++)
        #pragma unroll
        for (int ib = 0; ib < 4; ib++)
          acc[je][ib] += a4[ib].x * w4[je].x + a4[ib].y * w4[je].y +
                         a4[ib].z * w4[je].z + a4[ib].w * w4[je].w;
    }
    __syncthreads();
  }
  for (int je = 0; je < 8; je++) {
    int e = e0 + e_sub + 8 * je;
    for (int ib = 0; ib < 4; ib++)
      fcz[((size_t)kp * NB + b0 + ib) * NE + e] = acc[je][ib];
  }
}

// ---------------- finalize: logits, override, argmax, state, softmax ----------------
__global__ void k_final(const float* fcz, const float* fc_b, int* feed, int* ended,
                        float* out, int tstep)
{
  int b = blockIdx.x;
  int t = threadIdx.x;
  __shared__ float sval[256];
  __shared__ int   sidx[256];
  __shared__ float ssum[256];
  bool end = (ended[b] != 0);
  float v[4];
  int e_base = t * 4;
  #pragma unroll
  for (int j = 0; j < 4; j++) {
    int e = e_base + j;
    float s = fc_b[e];
    #pragma unroll
    for (int p = 0; p < 8; p++) s += fcz[((size_t)p * NB + b) * NE + e];
    v[j] = end ? (e == EOSL ? 1.f : 0.f) : s;
  }
  float bv = v[0]; int bi = e_base;
  #pragma unroll
  for (int j = 1; j < 4; j++) if (v[j] > bv) { bv = v[j]; bi = e_base + j; }
  sval[t] = bv; sidx[t] = bi;
  __syncthreads();
  for (int s = 128; s > 0; s >>= 1) {
    if (t < s) {
      float ov = sval[t + s]; int oi = sidx[t + s];
      if (ov > sval[t] || (ov == sval[t] && oi < sidx[t])) { sval[t] = ov; sidx[t] = oi; }
    }
    __syncthreads();
  }
  float m = sval[0]; int label = sidx[0];
  float ls = 0.f;
  #pragma unroll
  for (int j = 0; j < 4; j++) { v[j] = expf(v[j] - m); ls += v[j]; }
  ssum[t] = ls;
  __syncthreads();
  for (int s = 128; s > 0; s >>= 1) { if (t < s) ssum[t] += ssum[t + s]; __syncthreads(); }
  float inv = 1.f / ssum[0];
  float* orow = out + ((size_t)b * NT + tstep) * NE + e_base;
  #pragma unroll
  for (int j = 0; j < 4; j++) orow[j] = v[j] * inv;
  if (t == 0) {
    feed[b] = label;
    ended[b] = (end || label == EOSL) ? 1 : 0;
  }
}

extern "C" void kernel_launch(void* const* d_in, const int* in_sizes, int n_in,
                              void* d_out, int out_size, void* d_ws, size_t ws_size,
                              hipStream_t stream)
{
  const int*   yy    = (const int*)d_in[0];
  const float* h_t   = (const float*)d_in[1];
  const float* h_tr  = (const float*)d_in[2];
  const float* emb   = (const float*)d_in[4];
  const float* W_ih  = (const float*)d_in[5];
  const float* W_hh  = (const float*)d_in[6];
  const float* b_ih  = (const float*)d_in[7];
  const float* b_hh  = (const float*)d_in[8];
  const float* W_ihr = (const float*)d_in[9];
  const float* W_hhr = (const float*)d_in[10];
  const float* b_ihr = (const float*)d_in[11];
  const float* b_hhr = (const float*)d_in[12];
  const float* c0    = (const float*)d_in[13];
  const float* c0r   = (const float*)d_in[14];
  const float* fc_W  = (const float*)d_in[15];
  const float* fc_b  = (const float*)d_in[16];
  float* out = (float*)d_out;

  float* ws   = (float*)d_ws;
  float* zp   = ws + ZP_OFF;
  float* z0T  = ws + Z0T_OFF;
  float* hin  = ws + HIN_OFF;
  float* call = ws + C_OFF;
  float* Ht   = ws + HT_OFF;
  float* fcz  = ws + FCZ_OFF;
  float* bias = ws + BIAS_OFF;
  int* feed   = (int*)(ws + FEED_OFF);
  int* ended  = (int*)(ws + END_OFF);
  float* xh   = ws + XH_OFF;
  float* P0   = ws + P0_OFF;
  bool useP0 = ws_size >= TOTAL_P0_F * sizeof(float);

  const float* Wih0[2] = { W_ih,  W_ihr };
  const float* Whh0[2] = { W_hh,  W_hhr };
  const float* Wih1[2] = { W_ih + (size_t)G4 * NH,  W_ihr + (size_t)G4 * NH };
  const float* Whh1[2] = { W_hh + (size_t)G4 * NH,  W_hhr + (size_t)G4 * NH };

  k_init<<<2048, 256, 0, stream>>>(yy, h_t, h_tr, c0, c0r, b_ih, b_hh, b_ihr, b_hhr,
                                   hin, xh, useP0 ? 0 : 1, call, bias, feed, ended);
  if (useP0)
    k_p0<<<dim3(16, 64, 2), 256, 0, stream>>>(emb, W_ih, W_ihr, P0);

  GD d0, d1;
  for (int dir = 0; dir < 2; dir++) {
    if (useP0) {
      d0.in[dir] = hin + (size_t)dir * 2048 * 128;       // rows 0..1023 = h0
      for (int ks = 0; ks < 4; ks++) d0.W[dir * 4 + ks] = Whh0[dir] + ks * 256;
    } else {
      d0.in[dir] = xh + (size_t)dir * 2048 * 128;        // 0..1023 = x, 1024.. = h0
      d0.W[dir * 4 + 0] = Wih0[dir];
      d0.W[dir * 4 + 1] = Wih0[dir] + 512;
      d0.W[dir * 4 + 2] = Whh0[dir];
      d0.W[dir * 4 + 3] = Whh0[dir] + 512;
    }
    d1.in[dir] = hin + (size_t)dir * 2048 * 128;         // 0..1023 = h0, 1024.. = h1
    d1.W[dir * 4 + 0] = Wih1[dir];
    d1.W[dir * 4 + 1] = Wih1[dir] + 512;
    d1.W[dir * 4 + 2] = Whh1[dir];
    d1.W[dir * 4 + 3] = Whh1[dir] + 512;
  }
  d0.KB = useP0 ? 256 : 512;
  d1.KB = 512;

  for (int t = 0; t < NT; t++) {
    if (useP0)
      k_gatherT<<<dim3(16, 4, 2), 256, 0, stream>>>(P0, (long)NE * G4, G4, feed,
                                                    z0T, (long)G4 * NB, 0);
    else
      k_gatherT<<<dim3(4, 4, 2), 256, 0, stream>>>(emb, 0L, NE, feed,
                                                   xh, (long)2048 * 128, 0);
    k_gemm<<<dim3(32, 4, 2), 512, 0, stream>>>(d0, zp);
    k_gates<<<dim3(128, 2), 256, 0, stream>>>(zp, useP0 ? z0T : nullptr, bias,
                                              call, hin, 0,
                                              useP0 ? nullptr : xh, (long)2048 * 128, 1024);
    k_gemm<<<dim3(32, 4, 2), 512, 0, stream>>>(d1, zp);
    k_gates<<<dim3(128, 2), 256, 0, stream>>>(zp, nullptr, bias + 2 * 4096,
                                              call + (size_t)2 * 1024 * 128, hin, 1024,
                                              Ht, (long)1024 * 128, 0);
    k_fc<<<dim3(16, 8), 256, 0, stream>>>(Ht, fc_W, fcz);
    k_final<<<128, 256, 0, stream>>>(fcz, fc_b, feed, ended, out, t);
  }
}